// Round 1
// baseline (449.209 us; speedup 1.0000x reference)
//
#include <hip/hip_runtime.h>

#define NN     3072   // nodes
#define IND    512    // input dim
#define NH     8      // heads
#define DH     64     // head dim
#define HDTOT  512    // NH*DH
#define NA     8      // angles
#define THALF  256    // HDTOT/2

// ---------------------------------------------------------------------------
// Kernel 1: SM = softmax(S, axis=1), S is [8][256]. One block of 256 threads.
// ---------------------------------------------------------------------------
__global__ __launch_bounds__(256) void k_softmax_S(const float* __restrict__ S,
                                                   float* __restrict__ SM) {
    __shared__ float red[256];
    const int t = threadIdx.x;
    for (int a = 0; a < NA; ++a) {
        float v = S[a * THALF + t];
        red[t] = v; __syncthreads();
        for (int s = 128; s > 0; s >>= 1) {
            if (t < s) red[t] = fmaxf(red[t], red[t + s]);
            __syncthreads();
        }
        float mx = red[0]; __syncthreads();
        float e = __expf(v - mx);
        red[t] = e; __syncthreads();
        for (int s = 128; s > 0; s >>= 1) {
            if (t < s) red[t] += red[t + s];
            __syncthreads();
        }
        float inv = 1.0f / red[0]; __syncthreads();
        SM[a * THALF + t] = e * inv;
    }
}

// ---------------------------------------------------------------------------
// Kernel 2: QKV projection GEMM [3072,512] x [512,1536] with fused bias and
// (for Q,K) fused learned-rotation epilogue. Grid (48, 24), 256 threads.
// BM=BN=64, BK=16, per-thread 4x4 tile. BN=64 aligns exactly with one head,
// so the rotation partner column is always inside this block's tile.
// ---------------------------------------------------------------------------
__global__ __launch_bounds__(256) void k_qkv(
    const float* __restrict__ x,
    const float* __restrict__ Wq, const float* __restrict__ bq,
    const float* __restrict__ Wk, const float* __restrict__ bk,
    const float* __restrict__ Wv, const float* __restrict__ bv,
    const float* __restrict__ angles, const float* __restrict__ SM,
    float* __restrict__ Qm, float* __restrict__ Km, float* __restrict__ Vm)
{
    __shared__ float AsT[16 * 64];       // [k][m]
    __shared__ float Bs [16 * 64];       // [k][n]
    __shared__ float Cs [64 * 65];       // [m][d], padded stride 65
    __shared__ float SMl[NA * THALF];    // softmaxed S

    const int t   = threadIdx.x;
    const int m0  = blockIdx.x * 64;
    const int n0  = blockIdx.y * 64;     // global col in [0,1536)
    const int mat = n0 >> 9;             // 0=Q, 1=K, 2=V
    const int col0 = n0 & 511;           // col base within the matrix
    const float* __restrict__ W   = (mat == 0) ? Wq : (mat == 1) ? Wk : Wv;
    const float* __restrict__ bsv = (mat == 0) ? bq : (mat == 1) ? bk : bv;

    #pragma unroll
    for (int r = 0; r < 8; ++r) SMl[r * 256 + t] = SM[r * 256 + t];

    const int mi0 = (t >> 4) << 2;       // 0..60
    const int ni0 = (t & 15) << 2;       // 0..60
    const int am  = t >> 2;              // A-load row 0..63
    const int ak  = (t & 3) << 2;        // A-load k   0..12
    const int bkr = t >> 4;              // B-load k   0..15
    const int bnc = (t & 15) << 2;       // B-load col 0..60

    float acc[4][4];
    #pragma unroll
    for (int i = 0; i < 4; ++i)
        #pragma unroll
        for (int j = 0; j < 4; ++j) acc[i][j] = 0.0f;

    for (int k0 = 0; k0 < IND; k0 += 16) {
        __syncthreads();
        float4 av = *reinterpret_cast<const float4*>(&x[(size_t)(m0 + am) * IND + k0 + ak]);
        AsT[(ak + 0) * 64 + am] = av.x;
        AsT[(ak + 1) * 64 + am] = av.y;
        AsT[(ak + 2) * 64 + am] = av.z;
        AsT[(ak + 3) * 64 + am] = av.w;
        *reinterpret_cast<float4*>(&Bs[bkr * 64 + bnc]) =
            *reinterpret_cast<const float4*>(&W[(size_t)(k0 + bkr) * HDTOT + col0 + bnc]);
        __syncthreads();
        #pragma unroll
        for (int k = 0; k < 16; ++k) {
            float4 a4 = *reinterpret_cast<const float4*>(&AsT[k * 64 + mi0]);
            float4 b4 = *reinterpret_cast<const float4*>(&Bs [k * 64 + ni0]);
            acc[0][0] = fmaf(a4.x, b4.x, acc[0][0]);
            acc[0][1] = fmaf(a4.x, b4.y, acc[0][1]);
            acc[0][2] = fmaf(a4.x, b4.z, acc[0][2]);
            acc[0][3] = fmaf(a4.x, b4.w, acc[0][3]);
            acc[1][0] = fmaf(a4.y, b4.x, acc[1][0]);
            acc[1][1] = fmaf(a4.y, b4.y, acc[1][1]);
            acc[1][2] = fmaf(a4.y, b4.z, acc[1][2]);
            acc[1][3] = fmaf(a4.y, b4.w, acc[1][3]);
            acc[2][0] = fmaf(a4.z, b4.x, acc[2][0]);
            acc[2][1] = fmaf(a4.z, b4.y, acc[2][1]);
            acc[2][2] = fmaf(a4.z, b4.z, acc[2][2]);
            acc[2][3] = fmaf(a4.z, b4.w, acc[2][3]);
            acc[3][0] = fmaf(a4.w, b4.x, acc[3][0]);
            acc[3][1] = fmaf(a4.w, b4.y, acc[3][1]);
            acc[3][2] = fmaf(a4.w, b4.z, acc[3][2]);
            acc[3][3] = fmaf(a4.w, b4.w, acc[3][3]);
        }
    }

    float4 bb = *reinterpret_cast<const float4*>(&bsv[col0 + ni0]);

    if (mat == 2) {
        // V: no rotation, store directly
        #pragma unroll
        for (int mr = 0; mr < 4; ++mr) {
            float4 o = make_float4(acc[mr][0] + bb.x, acc[mr][1] + bb.y,
                                   acc[mr][2] + bb.z, acc[mr][3] + bb.w);
            *reinterpret_cast<float4*>(&Vm[(size_t)(m0 + mi0 + mr) * HDTOT + col0 + ni0]) = o;
        }
        return;
    }

    // stage raw tile for rotation (partner columns cross threads)
    #pragma unroll
    for (int mr = 0; mr < 4; ++mr) {
        Cs[(mi0 + mr) * 65 + ni0 + 0] = acc[mr][0] + bb.x;
        Cs[(mi0 + mr) * 65 + ni0 + 1] = acc[mr][1] + bb.y;
        Cs[(mi0 + mr) * 65 + ni0 + 2] = acc[mr][2] + bb.z;
        Cs[(mi0 + mr) * 65 + ni0 + 3] = acc[mr][3] + bb.w;
    }
    __syncthreads();

    float* __restrict__ dst = (mat == 0) ? Qm : Km;
    const int pidx = (col0 + ni0) >> 1;  // theta_half index of first pair

    #pragma unroll
    for (int mr = 0; mr < 4; ++mr) {
        const int n = m0 + mi0 + mr;
        // theta for the two (d,d+1) pairs this thread owns
        float th0 = 0.0f, th1 = 0.0f;
        #pragma unroll
        for (int j = 0; j < 8; ++j) {
            float aj = angles[n * NA + j];
            th0 = fmaf(aj, SMl[j * 256 + pidx],     th0);
            th1 = fmaf(aj, SMl[j * 256 + pidx + 1], th1);
        }
        float s0, c0, s1, c1;
        __sincosf(th0, &s0, &c0);
        __sincosf(th1, &s1, &c1);
        float o[4];
        #pragma unroll
        for (int cc = 0; cc < 4; ++cc) {
            const int d  = ni0 + cc;
            const int pd = (d < 32) ? (2 * d + 1) : (2 * (d - 32));
            float own = Cs[(mi0 + mr) * 65 + d];
            float pv  = Cs[(mi0 + mr) * 65 + pd];
            float q2  = (d < 32) ? -pv : pv;
            float ct  = (cc < 2) ? c0 : c1;
            float st  = (cc < 2) ? s0 : s1;
            o[cc] = own * ct + q2 * st;
        }
        *reinterpret_cast<float4*>(&dst[(size_t)n * HDTOT + col0 + ni0]) =
            make_float4(o[0], o[1], o[2], o[3]);
    }
}

// ---------------------------------------------------------------------------
// Kernel 3: attention. score[h,i,j] = (1/8) sum_d Qm[h*196608+i*64+d] *
// Km[h*196608+d*3072+j]; clip ±5; softmax over j; out = attn @ V (natural
// [N,H,D] layout). Scores bounded by clip -> no online max needed.
// Grid (96, 8) = (i-tiles of 32, heads). 256 threads.
// ---------------------------------------------------------------------------
__global__ __launch_bounds__(256) void k_attn(
    const float* __restrict__ Qm, const float* __restrict__ Km,
    const float* __restrict__ Vm, float* __restrict__ out)
{
    __shared__ float QsT[64 * 33];   // [d][i], stride 33
    __shared__ float Ks [64 * 64];   // [d][j]
    __shared__ float PsT[64 * 33];   // [j][i], stride 33
    __shared__ float Vs [64 * 64];   // [j][d]
    __shared__ float denom[32];

    const int t     = threadIdx.x;
    const int h     = blockIdx.y;
    const int ibase = blockIdx.x * 32;
    const size_t hb = (size_t)h * (DH * NN);   // head base in flat Q/K

    // Q tile 32 rows x 64 d, stored transposed
    #pragma unroll
    for (int r = 0; r < 8; ++r) {
        int flat = r * 256 + t;
        int i = flat >> 6;
        int d = flat & 63;
        QsT[d * 33 + i] = Qm[hb + (size_t)(ibase + i) * DH + d];
    }
    if (t < 32) denom[t] = 0.0f;

    const int ig  = t >> 4;        // 0..15 -> i pair
    const int jg  = t & 15;        // 0..15 -> j quad (score) / d quad (msg)
    const int i0  = ig * 2;
    const int j0l = jg * 4;

    float macc[2][4] = {{0.f,0.f,0.f,0.f},{0.f,0.f,0.f,0.f}};

    for (int jt = 0; jt < NN / 64; ++jt) {
        const int j0 = jt * 64;
        __syncthreads();   // previous msg phase done before overwriting Ks/Vs
        #pragma unroll
        for (int r = 0; r < 4; ++r) {
            int flat = r * 1024 + t * 4;
            int row  = flat >> 6;          // 0..63
            int cidx = flat & 63;          // 0..60 step 4
            *reinterpret_cast<float4*>(&Ks[row * 64 + cidx]) =
                *reinterpret_cast<const float4*>(&Km[hb + (size_t)row * NN + j0 + cidx]);
            *reinterpret_cast<float4*>(&Vs[row * 64 + cidx]) =
                *reinterpret_cast<const float4*>(&Vm[(size_t)(j0 + row) * HDTOT + h * DH + cidx]);
        }
        __syncthreads();

        // ---- score phase: this thread -> i in {i0,i0+1}, j in {j0l..j0l+3}
        float sacc[2][4] = {{0.f,0.f,0.f,0.f},{0.f,0.f,0.f,0.f}};
        #pragma unroll 8
        for (int d = 0; d < 64; ++d) {
            float q0 = QsT[d * 33 + i0];
            float q1 = QsT[d * 33 + i0 + 1];
            float4 k4 = *reinterpret_cast<const float4*>(&Ks[(d << 6) + j0l]);
            sacc[0][0] = fmaf(q0, k4.x, sacc[0][0]);
            sacc[0][1] = fmaf(q0, k4.y, sacc[0][1]);
            sacc[0][2] = fmaf(q0, k4.z, sacc[0][2]);
            sacc[0][3] = fmaf(q0, k4.w, sacc[0][3]);
            sacc[1][0] = fmaf(q1, k4.x, sacc[1][0]);
            sacc[1][1] = fmaf(q1, k4.y, sacc[1][1]);
            sacc[1][2] = fmaf(q1, k4.z, sacc[1][2]);
            sacc[1][3] = fmaf(q1, k4.w, sacc[1][3]);
        }
        float psum0 = 0.f, psum1 = 0.f;
        #pragma unroll
        for (int c = 0; c < 4; ++c) {
            float s0 = fminf(fmaxf(sacc[0][c] * 0.125f, -5.0f), 5.0f);
            float s1 = fminf(fmaxf(sacc[1][c] * 0.125f, -5.0f), 5.0f);
            float p0 = __expf(s0);
            float p1 = __expf(s1);
            PsT[(j0l + c) * 33 + i0]     = p0;
            PsT[(j0l + c) * 33 + i0 + 1] = p1;
            psum0 += p0;
            psum1 += p1;
        }
        #pragma unroll
        for (int m = 1; m < 16; m <<= 1) {
            psum0 += __shfl_xor(psum0, m, 64);
            psum1 += __shfl_xor(psum1, m, 64);
        }
        if (jg == 0) { denom[i0] += psum0; denom[i0 + 1] += psum1; }
        __syncthreads();

        // ---- msg phase: this thread -> i in {i0,i0+1}, d in {j0l..j0l+3}
        #pragma unroll 8
        for (int j = 0; j < 64; ++j) {
            float p0 = PsT[j * 33 + i0];
            float p1 = PsT[j * 33 + i0 + 1];
            float4 v4 = *reinterpret_cast<const float4*>(&Vs[(j << 6) + j0l]);
            macc[0][0] = fmaf(p0, v4.x, macc[0][0]);
            macc[0][1] = fmaf(p0, v4.y, macc[0][1]);
            macc[0][2] = fmaf(p0, v4.z, macc[0][2]);
            macc[0][3] = fmaf(p0, v4.w, macc[0][3]);
            macc[1][0] = fmaf(p1, v4.x, macc[1][0]);
            macc[1][1] = fmaf(p1, v4.y, macc[1][1]);
            macc[1][2] = fmaf(p1, v4.z, macc[1][2]);
            macc[1][3] = fmaf(p1, v4.w, macc[1][3]);
        }
    }
    __syncthreads();
    const float inv0 = 1.0f / denom[i0];
    const float inv1 = 1.0f / denom[i0 + 1];
    float4 o0 = make_float4(macc[0][0] * inv0, macc[0][1] * inv0,
                            macc[0][2] * inv0, macc[0][3] * inv0);
    float4 o1 = make_float4(macc[1][0] * inv1, macc[1][1] * inv1,
                            macc[1][2] * inv1, macc[1][3] * inv1);
    *reinterpret_cast<float4*>(&out[(size_t)(ibase + i0) * HDTOT + h * DH + j0l])     = o0;
    *reinterpret_cast<float4*>(&out[(size_t)(ibase + i0 + 1) * HDTOT + h * DH + j0l]) = o1;
}

// ---------------------------------------------------------------------------
extern "C" void kernel_launch(void* const* d_in, const int* in_sizes, int n_in,
                              void* d_out, int out_size, void* d_ws, size_t ws_size,
                              hipStream_t stream)
{
    const float* x      = (const float*)d_in[0];
    const float* angles = (const float*)d_in[1];
    const float* Wq     = (const float*)d_in[2];
    const float* bq     = (const float*)d_in[3];
    const float* Wk     = (const float*)d_in[4];
    const float* bk     = (const float*)d_in[5];
    const float* Wv     = (const float*)d_in[6];
    const float* bv     = (const float*)d_in[7];
    const float* S      = (const float*)d_in[8];
    float* out = (float*)d_out;

    float* ws = (float*)d_ws;
    float* SM = ws;                              // 2048 floats (pad to 4096)
    float* Qm = ws + 4096;                       // 3072*512 rotated Q
    float* Km = Qm + (size_t)NN * HDTOT;         // rotated K
    float* Vm = Km + (size_t)NN * HDTOT;         // V (bias-added)

    k_softmax_S<<<1, 256, 0, stream>>>(S, SM);
    k_qkv<<<dim3(48, 24), 256, 0, stream>>>(x, Wq, bq, Wk, bk, Wv, bv,
                                            angles, SM, Qm, Km, Vm);
    k_attn<<<dim3(96, 8), 256, 0, stream>>>(Qm, Km, Vm, out);
}

// Round 2
// 190.427 us; speedup vs baseline: 2.3590x; 2.3590x over previous
//
#include <hip/hip_runtime.h>
#include <hip/hip_bf16.h>

#define NN     3072   // nodes
#define IND    512    // input dim
#define NH     8      // heads
#define DH     64     // head dim
#define HDTOT  512    // NH*DH
#define NA     8      // angles
#define THALF  256    // HDTOT/2
#define DN     196608 // DH*NN

typedef float f32x4 __attribute__((ext_vector_type(4)));
typedef short bf16x8 __attribute__((ext_vector_type(8)));
typedef unsigned int u32x2 __attribute__((ext_vector_type(2)));

__device__ __forceinline__ unsigned short f2bf(float f) {
    union { float f; unsigned u; } a; a.f = f;
    unsigned u = a.u;
    return (unsigned short)((u + 0x7FFFu + ((u >> 16) & 1u)) >> 16);  // RNE
}

// ---------------------------------------------------------------------------
// Kernel 1: SM = softmax(S, axis=1), S is [8][256]. One block of 256 threads.
// ---------------------------------------------------------------------------
__global__ __launch_bounds__(256) void k_softmax_S(const float* __restrict__ S,
                                                   float* __restrict__ SM) {
    __shared__ float red[256];
    const int t = threadIdx.x;
    for (int a = 0; a < NA; ++a) {
        float v = S[a * THALF + t];
        red[t] = v; __syncthreads();
        for (int s = 128; s > 0; s >>= 1) {
            if (t < s) red[t] = fmaxf(red[t], red[t + s]);
            __syncthreads();
        }
        float mx = red[0]; __syncthreads();
        float e = __expf(v - mx);
        red[t] = e; __syncthreads();
        for (int s = 128; s > 0; s >>= 1) {
            if (t < s) red[t] += red[t + s];
            __syncthreads();
        }
        float inv = 1.0f / red[0]; __syncthreads();
        SM[a * THALF + t] = e * inv;
    }
}

// ---------------------------------------------------------------------------
// Kernel 2: QKV projection GEMM (f32 compute) with fused bias + rotation.
// Emits bf16 in MFMA-friendly layouts:
//   Qb : natural [N, HD]  (== the [H][N][D] reshape view, d contiguous)
//   KTb: [h][j][d]  (d contiguous; h=n'/384, d=nn/6, j=(nn%6)*512+c)
//   VTb: [h][d][n]  (n contiguous; true transpose of V)
// ---------------------------------------------------------------------------
__global__ __launch_bounds__(256) void k_qkv(
    const float* __restrict__ x,
    const float* __restrict__ Wq, const float* __restrict__ bq,
    const float* __restrict__ Wk, const float* __restrict__ bk,
    const float* __restrict__ Wv, const float* __restrict__ bv,
    const float* __restrict__ angles, const float* __restrict__ SM,
    unsigned short* __restrict__ Qb, unsigned short* __restrict__ KTb,
    unsigned short* __restrict__ VTb)
{
    __shared__ float AsT[16 * 64];       // [k][m]
    __shared__ float Bs [16 * 64];       // [k][n]
    __shared__ float Cs [64 * 65];       // [m][d], padded stride 65
    __shared__ float SMl[NA * THALF];    // softmaxed S

    const int t   = threadIdx.x;
    const int m0  = blockIdx.x * 64;
    const int n0  = blockIdx.y * 64;     // global col in [0,1536)
    const int mat = n0 >> 9;             // 0=Q, 1=K, 2=V
    const int col0 = n0 & 511;           // col base within the matrix
    const float* __restrict__ W   = (mat == 0) ? Wq : (mat == 1) ? Wk : Wv;
    const float* __restrict__ bsv = (mat == 0) ? bq : (mat == 1) ? bk : bv;

    #pragma unroll
    for (int r = 0; r < 8; ++r) SMl[r * 256 + t] = SM[r * 256 + t];

    const int mi0 = (t >> 4) << 2;       // 0..60
    const int ni0 = (t & 15) << 2;       // 0..60
    const int am  = t >> 2;              // A-load row 0..63
    const int ak  = (t & 3) << 2;        // A-load k   0..12
    const int bkr = t >> 4;              // B-load k   0..15
    const int bnc = (t & 15) << 2;       // B-load col 0..60

    float acc[4][4];
    #pragma unroll
    for (int i = 0; i < 4; ++i)
        #pragma unroll
        for (int j = 0; j < 4; ++j) acc[i][j] = 0.0f;

    for (int k0 = 0; k0 < IND; k0 += 16) {
        __syncthreads();
        float4 av = *reinterpret_cast<const float4*>(&x[(size_t)(m0 + am) * IND + k0 + ak]);
        AsT[(ak + 0) * 64 + am] = av.x;
        AsT[(ak + 1) * 64 + am] = av.y;
        AsT[(ak + 2) * 64 + am] = av.z;
        AsT[(ak + 3) * 64 + am] = av.w;
        *reinterpret_cast<float4*>(&Bs[bkr * 64 + bnc]) =
            *reinterpret_cast<const float4*>(&W[(size_t)(k0 + bkr) * HDTOT + col0 + bnc]);
        __syncthreads();
        #pragma unroll
        for (int k = 0; k < 16; ++k) {
            float4 a4 = *reinterpret_cast<const float4*>(&AsT[k * 64 + mi0]);
            float4 b4 = *reinterpret_cast<const float4*>(&Bs [k * 64 + ni0]);
            acc[0][0] = fmaf(a4.x, b4.x, acc[0][0]);
            acc[0][1] = fmaf(a4.x, b4.y, acc[0][1]);
            acc[0][2] = fmaf(a4.x, b4.z, acc[0][2]);
            acc[0][3] = fmaf(a4.x, b4.w, acc[0][3]);
            acc[1][0] = fmaf(a4.y, b4.x, acc[1][0]);
            acc[1][1] = fmaf(a4.y, b4.y, acc[1][1]);
            acc[1][2] = fmaf(a4.y, b4.z, acc[1][2]);
            acc[1][3] = fmaf(a4.y, b4.w, acc[1][3]);
            acc[2][0] = fmaf(a4.z, b4.x, acc[2][0]);
            acc[2][1] = fmaf(a4.z, b4.y, acc[2][1]);
            acc[2][2] = fmaf(a4.z, b4.z, acc[2][2]);
            acc[2][3] = fmaf(a4.z, b4.w, acc[2][3]);
            acc[3][0] = fmaf(a4.w, b4.x, acc[3][0]);
            acc[3][1] = fmaf(a4.w, b4.y, acc[3][1]);
            acc[3][2] = fmaf(a4.w, b4.z, acc[3][2]);
            acc[3][3] = fmaf(a4.w, b4.w, acc[3][3]);
        }
    }

    float4 bb = *reinterpret_cast<const float4*>(&bsv[col0 + ni0]);

    if (mat == 2) {
        // V: no rotation. Scatter to VTb[h][d][n] (d = ni0+cc, n = row).
        const int hV = col0 >> 6;
        #pragma unroll
        for (int mr = 0; mr < 4; ++mr) {
            const int nrow = m0 + mi0 + mr;
            float v[4] = {acc[mr][0] + bb.x, acc[mr][1] + bb.y,
                          acc[mr][2] + bb.z, acc[mr][3] + bb.w};
            #pragma unroll
            for (int cc = 0; cc < 4; ++cc)
                VTb[(size_t)hV * DN + (size_t)(ni0 + cc) * NN + nrow] = f2bf(v[cc]);
        }
        return;
    }

    // stage raw tile for rotation (partner columns cross threads)
    #pragma unroll
    for (int mr = 0; mr < 4; ++mr) {
        Cs[(mi0 + mr) * 65 + ni0 + 0] = acc[mr][0] + bb.x;
        Cs[(mi0 + mr) * 65 + ni0 + 1] = acc[mr][1] + bb.y;
        Cs[(mi0 + mr) * 65 + ni0 + 2] = acc[mr][2] + bb.z;
        Cs[(mi0 + mr) * 65 + ni0 + 3] = acc[mr][3] + bb.w;
    }
    __syncthreads();

    const int pidx = (col0 + ni0) >> 1;  // theta_half index of first pair
    const int hK = m0 / 384;             // head for the K reshape view (block-constant)

    #pragma unroll
    for (int mr = 0; mr < 4; ++mr) {
        const int n = m0 + mi0 + mr;
        float th0 = 0.0f, th1 = 0.0f;
        #pragma unroll
        for (int j = 0; j < 8; ++j) {
            float aj = angles[n * NA + j];
            th0 = fmaf(aj, SMl[j * 256 + pidx],     th0);
            th1 = fmaf(aj, SMl[j * 256 + pidx + 1], th1);
        }
        float s0, c0, s1, c1;
        __sincosf(th0, &s0, &c0);
        __sincosf(th1, &s1, &c1);
        float o[4];
        #pragma unroll
        for (int cc = 0; cc < 4; ++cc) {
            const int d  = ni0 + cc;
            const int pd = (d < 32) ? (2 * d + 1) : (2 * (d - 32));
            float own = Cs[(mi0 + mr) * 65 + d];
            float pv  = Cs[(mi0 + mr) * 65 + pd];
            float q2  = (d < 32) ? -pv : pv;
            float ct  = (cc < 2) ? c0 : c1;
            float st  = (cc < 2) ? s0 : s1;
            o[cc] = own * ct + q2 * st;
        }
        if (mat == 0) {
            // Q: natural layout, packed 8B store
            u32x2 w;
            w.x = (unsigned)f2bf(o[0]) | ((unsigned)f2bf(o[1]) << 16);
            w.y = (unsigned)f2bf(o[2]) | ((unsigned)f2bf(o[3]) << 16);
            *reinterpret_cast<u32x2*>(&Qb[(size_t)n * HDTOT + col0 + ni0]) = w;
        } else {
            // K: scatter to KTb[h][j][d]; consecutive c -> consecutive j, d fixed
            const int nn = n - hK * 384;
            const int d  = nn / 6;
            const int jr = (nn % 6) * 512 + col0 + ni0;
            #pragma unroll
            for (int cc = 0; cc < 4; ++cc)
                KTb[(size_t)hK * DN + (size_t)(jr + cc) * 64 + d] = f2bf(o[cc]);
        }
    }
}

// ---------------------------------------------------------------------------
// Kernel 3: MFMA attention. Per block: 1 head, 128 Q-rows, 4 waves x 32 rows.
// Computes S^T = mfma(KT-frag, Q-frag); exp(clip(s/8)); P^T via swizzled LDS;
// O^T = mfma(VT-frag, PT-frag). Denominator deferred to epilogue (clip bounds
// exp, no online max needed). Grid (24, 8).
// LDS: KT tile 8K | VT tile 8K | PT 4x4K  = 32 KiB, XOR-swizzled (row&7)<<4.
// ---------------------------------------------------------------------------
__global__ __launch_bounds__(256) void k_attn(
    const unsigned short* __restrict__ Qb,
    const unsigned short* __restrict__ KTb,
    const unsigned short* __restrict__ VTb,
    float* __restrict__ out)
{
    __shared__ __align__(16) char smem[32768];
    char* ktl = smem;                     // [64 j][64 d] bf16, swizzled
    char* vtl = smem + 8192;              // [64 d][64 j] bf16, swizzled
    const int t    = threadIdx.x;
    const int lane = t & 63;
    const int wv   = t >> 6;
    char* ptw = smem + 16384 + wv * 4096; // per-wave P^T [32 i][64 j] bf16, swizzled

    const int h     = blockIdx.y;
    const int qbase = blockIdx.x * 128;
    const int l15   = lane & 15;
    const int lg    = lane >> 4;          // 0..3
    const int r8    = lane >> 3;          // staging row 0..7
    const int c8    = lane & 7;           // staging chunk

    // Q fragments (held in registers for the whole kernel)
    bf16x8 qf[2][2];
    #pragma unroll
    for (int im = 0; im < 2; ++im)
        #pragma unroll
        for (int ks = 0; ks < 2; ++ks) {
            const int i = qbase + wv * 32 + im * 16 + l15;
            qf[im][ks] = *reinterpret_cast<const bf16x8*>(
                Qb + (size_t)h * DN + (size_t)i * 64 + ks * 32 + lg * 8);
        }

    f32x4 oacc[2][4];
    #pragma unroll
    for (int im = 0; im < 2; ++im)
        #pragma unroll
        for (int db = 0; db < 4; ++db)
            oacc[im][db] = (f32x4){0.f, 0.f, 0.f, 0.f};
    float dpart[2] = {0.f, 0.f};

    for (int jt = 0; jt < NN / 64; ++jt) {
        const int j0 = jt * 64;
        __syncthreads();   // all waves done reading tiles before overwrite
        // Stage KT tile rows [wv*16, wv*16+16): linear LDS dest, pre-swizzled
        // global source (chunk c8 ^ (row&7)) so swizzled reads see right data.
        #pragma unroll
        for (int cc = 0; cc < 2; ++cc) {
            const int row   = wv * 16 + cc * 8 + r8;      // j within tile
            const int chunk = c8 ^ (row & 7);
            const unsigned short* src =
                KTb + (size_t)h * DN + (size_t)(j0 + row) * 64 + chunk * 8;
            __builtin_amdgcn_global_load_lds(
                (const __attribute__((address_space(1))) unsigned int*)src,
                (__attribute__((address_space(3))) unsigned int*)(ktl + (wv * 16 + cc * 8) * 128),
                16, 0, 0);
        }
        #pragma unroll
        for (int cc = 0; cc < 2; ++cc) {
            const int row   = wv * 16 + cc * 8 + r8;      // d
            const int chunk = c8 ^ (row & 7);
            const unsigned short* src =
                VTb + (size_t)h * DN + (size_t)row * NN + j0 + chunk * 8;
            __builtin_amdgcn_global_load_lds(
                (const __attribute__((address_space(1))) unsigned int*)src,
                (__attribute__((address_space(3))) unsigned int*)(vtl + (wv * 16 + cc * 8) * 128),
                16, 0, 0);
        }
        __syncthreads();   // vmcnt drained -> tiles visible

        // ---- score: S^T[j,i] accumulated over d (2 k-steps of 32)
        f32x4 sac[2][4];
        #pragma unroll
        for (int im = 0; im < 2; ++im)
            #pragma unroll
            for (int jb = 0; jb < 4; ++jb)
                sac[im][jb] = (f32x4){0.f, 0.f, 0.f, 0.f};
        #pragma unroll
        for (int ks = 0; ks < 2; ++ks) {
            bf16x8 kf[4];
            #pragma unroll
            for (int jb = 0; jb < 4; ++jb) {
                const int row = jb * 16 + l15;
                int off = row * 128 + ks * 64 + lg * 16;
                off ^= (row & 7) << 4;
                kf[jb] = *reinterpret_cast<const bf16x8*>(ktl + off);
            }
            #pragma unroll
            for (int im = 0; im < 2; ++im)
                #pragma unroll
                for (int jb = 0; jb < 4; ++jb)
                    sac[im][jb] = __builtin_amdgcn_mfma_f32_16x16x32_bf16(
                        kf[jb], qf[im][ks], sac[im][jb], 0, 0, 0);
        }

        // ---- softmax piece: p = exp(clip(s/8, ±5)); accumulate denominator;
        //      write P^T (bf16) to per-wave swizzled LDS
        #pragma unroll
        for (int im = 0; im < 2; ++im) {
            const int row = im * 16 + l15;   // i within wave's 32 rows
            #pragma unroll
            for (int jb = 0; jb < 4; ++jb) {
                float p[4];
                #pragma unroll
                for (int r = 0; r < 4; ++r) {
                    float sc = sac[im][jb][r] * 0.125f;
                    sc = fminf(fmaxf(sc, -5.0f), 5.0f);
                    p[r] = __expf(sc);
                }
                dpart[im] += (p[0] + p[1]) + (p[2] + p[3]);
                u32x2 w;
                w.x = (unsigned)f2bf(p[0]) | ((unsigned)f2bf(p[1]) << 16);
                w.y = (unsigned)f2bf(p[2]) | ((unsigned)f2bf(p[3]) << 16);
                int off = row * 128 + jb * 32 + lg * 8;
                off ^= (row & 7) << 4;
                *reinterpret_cast<u32x2*>(ptw + off) = w;
            }
        }

        // ---- PV: O^T[d,i] += V^T[d,j] * P^T[j,i]  (wave-private PT, lgkmcnt
        //      ordering inserted by compiler)
        bf16x8 pf[2][2];
        #pragma unroll
        for (int im = 0; im < 2; ++im)
            #pragma unroll
            for (int js = 0; js < 2; ++js) {
                const int row = im * 16 + l15;
                int off = row * 128 + js * 64 + lg * 16;
                off ^= (row & 7) << 4;
                pf[im][js] = *reinterpret_cast<const bf16x8*>(ptw + off);
            }
        #pragma unroll
        for (int js = 0; js < 2; ++js)
            #pragma unroll
            for (int db = 0; db < 4; ++db) {
                const int row = db * 16 + l15;
                int off = row * 128 + js * 64 + lg * 16;
                off ^= (row & 7) << 4;
                bf16x8 vf = *reinterpret_cast<const bf16x8*>(vtl + off);
                #pragma unroll
                for (int im = 0; im < 2; ++im)
                    oacc[im][db] = __builtin_amdgcn_mfma_f32_16x16x32_bf16(
                        vf, pf[im][js], oacc[im][db], 0, 0, 0);
            }
    }

    // ---- epilogue: finish denominators (4 lane-groups hold disjoint j
    //      partials for the same i) and write O
    #pragma unroll
    for (int im = 0; im < 2; ++im) {
        float d = dpart[im];
        d += __shfl_xor(d, 16);
        d += __shfl_xor(d, 32);
        const float inv = 1.0f / d;
        const int i = qbase + wv * 32 + im * 16 + l15;
        #pragma unroll
        for (int db = 0; db < 4; ++db) {
            float4 o;
            o.x = oacc[im][db][0] * inv;
            o.y = oacc[im][db][1] * inv;
            o.z = oacc[im][db][2] * inv;
            o.w = oacc[im][db][3] * inv;
            *reinterpret_cast<float4*>(
                &out[(size_t)i * HDTOT + h * DH + db * 16 + lg * 4]) = o;
        }
    }
}

// ---------------------------------------------------------------------------
extern "C" void kernel_launch(void* const* d_in, const int* in_sizes, int n_in,
                              void* d_out, int out_size, void* d_ws, size_t ws_size,
                              hipStream_t stream)
{
    const float* x      = (const float*)d_in[0];
    const float* angles = (const float*)d_in[1];
    const float* Wq     = (const float*)d_in[2];
    const float* bq     = (const float*)d_in[3];
    const float* Wk     = (const float*)d_in[4];
    const float* bk     = (const float*)d_in[5];
    const float* Wv     = (const float*)d_in[6];
    const float* bv     = (const float*)d_in[7];
    const float* S      = (const float*)d_in[8];
    float* out = (float*)d_out;

    float* ws = (float*)d_ws;
    float* SM = ws;                                    // 4096 f32 (16 KB)
    unsigned short* Qb  = (unsigned short*)(ws + 4096);
    unsigned short* KTb = Qb  + (size_t)NN * HDTOT;    // 3 MB each
    unsigned short* VTb = KTb + (size_t)NN * HDTOT;

    k_softmax_S<<<1, 256, 0, stream>>>(S, SM);
    k_qkv<<<dim3(48, 24), 256, 0, stream>>>(x, Wq, bq, Wk, bk, Wv, bv,
                                            angles, SM, Qb, KTb, VTb);
    k_attn<<<dim3(24, 8), 256, 0, stream>>>(Qb, KTb, VTb, out);
}

// Round 4
// 78.538 us; speedup vs baseline: 5.7196x; 2.4246x over previous
//
#include <hip/hip_runtime.h>

#define NN     3072   // nodes
#define IND    512    // input dim
#define NH     8      // heads
#define DH     64     // head dim
#define HDTOT  512    // NH*DH
#define NA     8      // angles
#define THALF  256    // HDTOT/2
#define DN     196608 // DH*NN

typedef float f32x4 __attribute__((ext_vector_type(4)));
typedef short bf16x8 __attribute__((ext_vector_type(8)));
typedef unsigned int u32x2 __attribute__((ext_vector_type(2)));

__device__ __forceinline__ unsigned short f2bf(float f) {
    union { float f; unsigned u; } a; a.f = f;
    unsigned u = a.u;
    return (unsigned short)((u + 0x7FFFu + ((u >> 16) & 1u)) >> 16);  // RNE
}
__device__ __forceinline__ unsigned pack2(float a, float b) {
    return (unsigned)f2bf(a) | ((unsigned)f2bf(b) << 16);
}

// ---------------------------------------------------------------------------
// k_prep: block 0 -> softmax(S); blocks 1..768 -> x f32->bf16; blocks
// 769..1536 -> W transpose+convert to WTb[1536][512] bf16 (k-contiguous).
// ---------------------------------------------------------------------------
__global__ __launch_bounds__(256) void k_prep(
    const float* __restrict__ S, const float* __restrict__ x,
    const float* __restrict__ Wq, const float* __restrict__ Wk,
    const float* __restrict__ Wv,
    float* __restrict__ SM, unsigned short* __restrict__ xb,
    unsigned short* __restrict__ WTb)
{
    __shared__ float sh[32 * 33];
    const int b = blockIdx.x, t = threadIdx.x;
    if (b == 0) {
        for (int a = 0; a < NA; ++a) {
            float v = S[a * THALF + t];
            sh[t] = v; __syncthreads();
            for (int s = 128; s > 0; s >>= 1) {
                if (t < s) sh[t] = fmaxf(sh[t], sh[t + s]);
                __syncthreads();
            }
            float mx = sh[0]; __syncthreads();
            float e = __expf(v - mx);
            sh[t] = e; __syncthreads();
            for (int s = 128; s > 0; s >>= 1) {
                if (t < s) sh[t] += sh[t + s];
                __syncthreads();
            }
            float inv = 1.0f / sh[0]; __syncthreads();
            SM[a * THALF + t] = e * inv;
        }
    } else if (b <= 768) {
        const size_t base = ((size_t)(b - 1) * 256 + t) * 8;
        float4 v0 = *reinterpret_cast<const float4*>(&x[base]);
        float4 v1 = *reinterpret_cast<const float4*>(&x[base + 4]);
        uint4 w;
        w.x = pack2(v0.x, v0.y); w.y = pack2(v0.z, v0.w);
        w.z = pack2(v1.x, v1.y); w.w = pack2(v1.z, v1.w);
        *reinterpret_cast<uint4*>(&xb[base]) = w;
    } else {
        const int b2 = b - 769;
        const int kt = b2 & 15, nt = b2 >> 4;
        const int k0 = kt * 32, n0 = nt * 32;
        const float* __restrict__ W = (n0 < 512) ? Wq : (n0 < 1024 ? Wk : Wv);
        const int nc0 = n0 & 511;
        const int r = t >> 5, c = t & 31;
        #pragma unroll
        for (int i = 0; i < 4; ++i)
            sh[(r + i * 8) * 33 + c] = W[(size_t)(k0 + r + i * 8) * HDTOT + nc0 + c];
        __syncthreads();
        #pragma unroll
        for (int i = 0; i < 4; ++i) {
            const int nr = r + i * 8;
            WTb[(size_t)(n0 + nr) * IND + k0 + c] = f2bf(sh[c * 33 + nr]);
        }
    }
}

// ---------------------------------------------------------------------------
// k_qkv_mfma: C[3072,1536] = xb @ W (bf16 MFMA, f32 accum), fused bias +
// rotation epilogue. BM=128, BN=64, BK=64, 4 waves (2x2), per-wave 64x32.
// Grid (24, 24). Outputs: Qb natural, KTb[h][j][d], VTb[h][d][n].
// All barriers are __syncthreads() (full vmcnt/lgkmcnt drain — safe).
// ---------------------------------------------------------------------------
__global__ __launch_bounds__(256) void k_qkv_mfma(
    const unsigned short* __restrict__ xb,
    const unsigned short* __restrict__ WTb,
    const float* __restrict__ bq, const float* __restrict__ bk,
    const float* __restrict__ bv,
    const float* __restrict__ angles, const float* __restrict__ SM,
    unsigned short* __restrict__ Qb, unsigned short* __restrict__ KTb,
    unsigned short* __restrict__ VTb)
{
    __shared__ __align__(16) char lds[41472];
    char* At  = lds;                       // [128][64] bf16 swizzled (16 KB)
    char* Bt  = lds + 16384;               // [64][64]  bf16 swizzled (8 KB)
    float* Cs = (float*)lds;               // [128][65] f32 (aliases At/Bt)
    float* SMl = (float*)(lds + 33280);    // 2048 f32

    const int t = threadIdx.x;
    const int lane = t & 63;
    const int wv = t >> 6;
    const int wrow = wv >> 1, wcol = wv & 1;
    const int l15 = lane & 15, lg = lane >> 4;
    const int r8 = lane >> 3, c8 = lane & 7;

    const int m0 = blockIdx.x * 128;
    const int n0 = blockIdx.y * 64;
    const int mat = n0 >> 9;              // 0=Q 1=K 2=V
    const int c0 = n0 & 511;

    if (mat < 2) {
        #pragma unroll
        for (int r = 0; r < 8; ++r) SMl[r * 256 + t] = SM[r * 256 + t];
    }

    f32x4 acc[4][2];
    #pragma unroll
    for (int mf = 0; mf < 4; ++mf)
        #pragma unroll
        for (int nf = 0; nf < 2; ++nf)
            acc[mf][nf] = (f32x4){0.f, 0.f, 0.f, 0.f};

    for (int kt = 0; kt < 8; ++kt) {
        __syncthreads();
        #pragma unroll
        for (int i = 0; i < 4; ++i) {
            const int row = wv * 32 + i * 8 + r8;
            const unsigned short* src =
                xb + (size_t)(m0 + row) * IND + kt * 64 + (c8 ^ (row & 7)) * 8;
            __builtin_amdgcn_global_load_lds(
                (const __attribute__((address_space(1))) unsigned int*)src,
                (__attribute__((address_space(3))) unsigned int*)(At + (wv * 32 + i * 8) * 128),
                16, 0, 0);
        }
        #pragma unroll
        for (int i = 0; i < 2; ++i) {
            const int row = wv * 16 + i * 8 + r8;
            const unsigned short* src =
                WTb + (size_t)(n0 + row) * IND + kt * 64 + (c8 ^ (row & 7)) * 8;
            __builtin_amdgcn_global_load_lds(
                (const __attribute__((address_space(1))) unsigned int*)src,
                (__attribute__((address_space(3))) unsigned int*)(Bt + (wv * 16 + i * 8) * 128),
                16, 0, 0);
        }
        __syncthreads();
        #pragma unroll
        for (int ks = 0; ks < 2; ++ks) {
            bf16x8 af[4], bfr[2];
            #pragma unroll
            for (int mf = 0; mf < 4; ++mf) {
                const int row = wrow * 64 + mf * 16 + l15;
                int off = row * 128 + ks * 64 + lg * 16;
                off ^= (row & 7) << 4;
                af[mf] = *reinterpret_cast<const bf16x8*>(At + off);
            }
            #pragma unroll
            for (int nf = 0; nf < 2; ++nf) {
                const int row = wcol * 32 + nf * 16 + l15;
                int off = row * 128 + ks * 64 + lg * 16;
                off ^= (row & 7) << 4;
                bfr[nf] = *reinterpret_cast<const bf16x8*>(Bt + off);
            }
            #pragma unroll
            for (int mf = 0; mf < 4; ++mf)
                #pragma unroll
                for (int nf = 0; nf < 2; ++nf)
                    acc[mf][nf] = __builtin_amdgcn_mfma_f32_16x16x32_bf16(
                        af[mf], bfr[nf], acc[mf][nf], 0, 0, 0);
        }
    }

    if (mat == 2) {
        // V: direct store from accumulators to VTb[h][d][n] (n-contiguous)
        #pragma unroll
        for (int nf = 0; nf < 2; ++nf) {
            const int cg = c0 + wcol * 32 + nf * 16 + l15;
            const float b = bv[cg];
            const int hV = cg >> 6, dd = cg & 63;
            #pragma unroll
            for (int mf = 0; mf < 4; ++mf) {
                const int nb = m0 + wrow * 64 + mf * 16 + lg * 4;
                u32x2 w;
                w.x = pack2(acc[mf][nf][0] + b, acc[mf][nf][1] + b);
                w.y = pack2(acc[mf][nf][2] + b, acc[mf][nf][3] + b);
                *reinterpret_cast<u32x2*>(&VTb[(size_t)hV * DN + (size_t)dd * NN + nb]) = w;
            }
        }
        return;
    }

    // Q/K: stage biased tile to Cs, then rotation epilogue
    __syncthreads();   // frag reads of At/Bt done before aliasing as Cs
    const float* __restrict__ bsv = mat ? bk : bq;
    #pragma unroll
    for (int nf = 0; nf < 2; ++nf) {
        const int colc = wcol * 32 + nf * 16 + l15;
        const float b = bsv[c0 + colc];
        #pragma unroll
        for (int mf = 0; mf < 4; ++mf) {
            const int rb = wrow * 64 + mf * 16 + lg * 4;
            #pragma unroll
            for (int r = 0; r < 4; ++r)
                Cs[(rb + r) * 65 + colc] = acc[mf][nf][r] + b;
        }
    }
    __syncthreads();

    const int ni0 = (t & 15) * 4;
    const int rbase = (t >> 4) * 8;
    const int pidx = (c0 + ni0) >> 1;
    const int hK = m0 / 384;

    #pragma unroll
    for (int rr = 0; rr < 8; ++rr) {
        const int row = rbase + rr;
        const int n = m0 + row;
        const float4 a0 = *reinterpret_cast<const float4*>(&angles[n * NA]);
        const float4 a1 = *reinterpret_cast<const float4*>(&angles[n * NA + 4]);
        float th0, th1;
        th0 = a0.x * SMl[0 * 256 + pidx];
        th0 = fmaf(a0.y, SMl[1 * 256 + pidx], th0);
        th0 = fmaf(a0.z, SMl[2 * 256 + pidx], th0);
        th0 = fmaf(a0.w, SMl[3 * 256 + pidx], th0);
        th0 = fmaf(a1.x, SMl[4 * 256 + pidx], th0);
        th0 = fmaf(a1.y, SMl[5 * 256 + pidx], th0);
        th0 = fmaf(a1.z, SMl[6 * 256 + pidx], th0);
        th0 = fmaf(a1.w, SMl[7 * 256 + pidx], th0);
        th1 = a0.x * SMl[0 * 256 + pidx + 1];
        th1 = fmaf(a0.y, SMl[1 * 256 + pidx + 1], th1);
        th1 = fmaf(a0.z, SMl[2 * 256 + pidx + 1], th1);
        th1 = fmaf(a0.w, SMl[3 * 256 + pidx + 1], th1);
        th1 = fmaf(a1.x, SMl[4 * 256 + pidx + 1], th1);
        th1 = fmaf(a1.y, SMl[5 * 256 + pidx + 1], th1);
        th1 = fmaf(a1.z, SMl[6 * 256 + pidx + 1], th1);
        th1 = fmaf(a1.w, SMl[7 * 256 + pidx + 1], th1);
        float s0, c0f, s1, c1f;
        __sincosf(th0, &s0, &c0f);
        __sincosf(th1, &s1, &c1f);
        float o[4];
        #pragma unroll
        for (int cc = 0; cc < 4; ++cc) {
            const int d = ni0 + cc;
            const int pd = (d < 32) ? (2 * d + 1) : (2 * (d - 32));
            float own = Cs[row * 65 + d];
            float pv  = Cs[row * 65 + pd];
            float q2  = (d < 32) ? -pv : pv;
            float ct  = (cc < 2) ? c0f : c1f;
            float st  = (cc < 2) ? s0 : s1;
            o[cc] = own * ct + q2 * st;
        }
        if (mat == 0) {
            u32x2 w;
            w.x = pack2(o[0], o[1]);
            w.y = pack2(o[2], o[3]);
            *reinterpret_cast<u32x2*>(&Qb[(size_t)n * HDTOT + c0 + ni0]) = w;
        } else {
            const int nn = n - hK * 384;
            const int dk = nn / 6;
            const int jb = (nn - dk * 6) * 512 + c0 + ni0;
            #pragma unroll
            for (int cc = 0; cc < 4; ++cc)
                KTb[(size_t)hK * DN + (size_t)(jb + cc) * 64 + dk] = f2bf(o[cc]);
        }
    }
}

// ---------------------------------------------------------------------------
// k_attn: MFMA attention, double-buffered K/V tiles, ONE __syncthreads per
// tile (full drain -> race-free); stage for tile jj+1 issued right after the
// barrier so HBM latency hides under tile jj's compute. j-split over
// blockIdx.z; PARTIAL writes unnormalized O + denominators to workspace.
// ---------------------------------------------------------------------------
template<int TILES, bool PARTIAL>
__global__ __launch_bounds__(256) void k_attn(
    const unsigned short* __restrict__ Qb,
    const unsigned short* __restrict__ KTb,
    const unsigned short* __restrict__ VTb,
    float* __restrict__ outp, float* __restrict__ Dp)
{
    __shared__ __align__(16) char smem[49152];
    const int t = threadIdx.x;
    const int lane = t & 63;
    const int wv = t >> 6;
    char* ptw = smem + 32768 + wv * 4096;  // per-wave P [i][j] bf16, swizzled

    const int h = blockIdx.y;
    const int qbase = blockIdx.x * 128;
    const int z = blockIdx.z;
    const int jt0 = z * TILES;
    const int l15 = lane & 15;
    const int lg = lane >> 4;
    const int r8 = lane >> 3;
    const int c8 = lane & 7;

    bf16x8 qf[2][2];
    #pragma unroll
    for (int im = 0; im < 2; ++im)
        #pragma unroll
        for (int ks = 0; ks < 2; ++ks) {
            const int i = qbase + wv * 32 + im * 16 + l15;
            qf[im][ks] = *reinterpret_cast<const bf16x8*>(
                Qb + (size_t)h * DN + (size_t)i * 64 + ks * 32 + lg * 8);
        }

    f32x4 oacc[2][4];
    #pragma unroll
    for (int im = 0; im < 2; ++im)
        #pragma unroll
        for (int db = 0; db < 4; ++db)
            oacc[im][db] = (f32x4){0.f, 0.f, 0.f, 0.f};
    float dpart[2] = {0.f, 0.f};

    auto STAGE = [&](int buf, int jt) {
        const int j0 = jt * 64;
        char* ktl = smem + buf * 8192;
        char* vtl = smem + 16384 + buf * 8192;
        #pragma unroll
        for (int cc = 0; cc < 2; ++cc) {
            const int row = wv * 16 + cc * 8 + r8;
            const int chunk = c8 ^ (row & 7);
            const unsigned short* srcK =
                KTb + (size_t)h * DN + (size_t)(j0 + row) * 64 + chunk * 8;
            __builtin_amdgcn_global_load_lds(
                (const __attribute__((address_space(1))) unsigned int*)srcK,
                (__attribute__((address_space(3))) unsigned int*)(ktl + (wv * 16 + cc * 8) * 128),
                16, 0, 0);
            const unsigned short* srcV =
                VTb + (size_t)h * DN + (size_t)row * NN + j0 + chunk * 8;
            __builtin_amdgcn_global_load_lds(
                (const __attribute__((address_space(1))) unsigned int*)srcV,
                (__attribute__((address_space(3))) unsigned int*)(vtl + (wv * 16 + cc * 8) * 128),
                16, 0, 0);
        }
    };

    STAGE(0, jt0);

    int cur = 0;
    for (int jj = 0; jj < TILES; ++jj) {
        __syncthreads();   // drains stage of buf `cur` + all waves past reads of buf cur^1
        if (jj + 1 < TILES) STAGE(cur ^ 1, jt0 + jj + 1);
        char* ktl = smem + cur * 8192;
        char* vtl = smem + 16384 + cur * 8192;

        // ---- score: S^T[j,i] over d (2 k-steps)
        f32x4 sac[2][4];
        #pragma unroll
        for (int im = 0; im < 2; ++im)
            #pragma unroll
            for (int jb = 0; jb < 4; ++jb)
                sac[im][jb] = (f32x4){0.f, 0.f, 0.f, 0.f};
        #pragma unroll
        for (int ks = 0; ks < 2; ++ks) {
            bf16x8 kf[4];
            #pragma unroll
            for (int jb = 0; jb < 4; ++jb) {
                const int row = jb * 16 + l15;
                int off = row * 128 + ks * 64 + lg * 16;
                off ^= (row & 7) << 4;
                kf[jb] = *reinterpret_cast<const bf16x8*>(ktl + off);
            }
            #pragma unroll
            for (int im = 0; im < 2; ++im)
                #pragma unroll
                for (int jb = 0; jb < 4; ++jb)
                    sac[im][jb] = __builtin_amdgcn_mfma_f32_16x16x32_bf16(
                        kf[jb], qf[im][ks], sac[im][jb], 0, 0, 0);
        }

        // ---- softmax piece -> P bf16 in per-wave LDS
        #pragma unroll
        for (int im = 0; im < 2; ++im) {
            const int row = im * 16 + l15;
            #pragma unroll
            for (int jb = 0; jb < 4; ++jb) {
                float p[4];
                #pragma unroll
                for (int r = 0; r < 4; ++r) {
                    float sc = sac[im][jb][r] * 0.125f;
                    sc = fminf(fmaxf(sc, -5.0f), 5.0f);
                    p[r] = __expf(sc);
                }
                dpart[im] += (p[0] + p[1]) + (p[2] + p[3]);
                u32x2 w;
                w.x = pack2(p[0], p[1]);
                w.y = pack2(p[2], p[3]);
                int off = row * 128 + jb * 32 + lg * 8;
                off ^= (row & 7) << 4;
                *reinterpret_cast<u32x2*>(ptw + off) = w;
            }
        }

        // ---- PV: O^T[d,i] += V^T[d,j] * P[i][j]-as-B
        bf16x8 pf[2][2];
        #pragma unroll
        for (int im = 0; im < 2; ++im)
            #pragma unroll
            for (int js = 0; js < 2; ++js) {
                const int row = im * 16 + l15;
                int off = row * 128 + js * 64 + lg * 16;
                off ^= (row & 7) << 4;
                pf[im][js] = *reinterpret_cast<const bf16x8*>(ptw + off);
            }
        #pragma unroll
        for (int js = 0; js < 2; ++js)
            #pragma unroll
            for (int db = 0; db < 4; ++db) {
                const int row = db * 16 + l15;
                int off = row * 128 + js * 64 + lg * 16;
                off ^= (row & 7) << 4;
                bf16x8 vf = *reinterpret_cast<const bf16x8*>(vtl + off);
                #pragma unroll
                for (int im = 0; im < 2; ++im)
                    oacc[im][db] = __builtin_amdgcn_mfma_f32_16x16x32_bf16(
                        vf, pf[im][js], oacc[im][db], 0, 0, 0);
            }
        cur ^= 1;
    }

    // ---- epilogue
    #pragma unroll
    for (int im = 0; im < 2; ++im) {
        float d = dpart[im];
        d += __shfl_xor(d, 16);
        d += __shfl_xor(d, 32);
        const int i = qbase + wv * 32 + im * 16 + l15;
        if (PARTIAL) {
            if (lg == 0) Dp[((size_t)z * NH + h) * NN + i] = d;
            const size_t base = (((size_t)z * NH + h) * NN + i) * 64;
            #pragma unroll
            for (int db = 0; db < 4; ++db) {
                float4 o;
                o.x = oacc[im][db][0]; o.y = oacc[im][db][1];
                o.z = oacc[im][db][2]; o.w = oacc[im][db][3];
                *reinterpret_cast<float4*>(&outp[base + db * 16 + lg * 4]) = o;
            }
        } else {
            const float inv = 1.0f / d;
            #pragma unroll
            for (int db = 0; db < 4; ++db) {
                float4 o;
                o.x = oacc[im][db][0] * inv; o.y = oacc[im][db][1] * inv;
                o.z = oacc[im][db][2] * inv; o.w = oacc[im][db][3] * inv;
                *reinterpret_cast<float4*>(
                    &outp[(size_t)i * HDTOT + h * DH + db * 16 + lg * 4]) = o;
            }
        }
    }
}

// ---------------------------------------------------------------------------
// k_reduce: out = (sum_z Opart) / (sum_z Dpart)
// ---------------------------------------------------------------------------
__global__ __launch_bounds__(256) void k_reduce(
    const float* __restrict__ Op, const float* __restrict__ Dp,
    float* __restrict__ out, int NZ)
{
    const int g = blockIdx.x * 256 + threadIdx.x;   // < 393216
    const int i = g >> 7;
    const int rem = g & 127;
    const int h = rem >> 4;
    const int dc = rem & 15;
    f32x4 o = (f32x4){0.f, 0.f, 0.f, 0.f};
    float D = 0.f;
    for (int zz = 0; zz < NZ; ++zz) {
        o += *reinterpret_cast<const f32x4*>(
            &Op[(((size_t)zz * NH + h) * NN + i) * 64 + dc * 4]);
        D += Dp[((size_t)zz * NH + h) * NN + i];
    }
    const float inv = 1.0f / D;
    float4 w;
    w.x = o[0] * inv; w.y = o[1] * inv; w.z = o[2] * inv; w.w = o[3] * inv;
    *reinterpret_cast<float4*>(&out[(size_t)i * HDTOT + h * 64 + dc * 4]) = w;
}

// ---------------------------------------------------------------------------
extern "C" void kernel_launch(void* const* d_in, const int* in_sizes, int n_in,
                              void* d_out, int out_size, void* d_ws, size_t ws_size,
                              hipStream_t stream)
{
    const float* x      = (const float*)d_in[0];
    const float* angles = (const float*)d_in[1];
    const float* Wq     = (const float*)d_in[2];
    const float* bq     = (const float*)d_in[3];
    const float* Wk     = (const float*)d_in[4];
    const float* bk     = (const float*)d_in[5];
    const float* Wv     = (const float*)d_in[6];
    const float* bv     = (const float*)d_in[7];
    const float* S      = (const float*)d_in[8];
    float* out = (float*)d_out;

    float* ws = (float*)d_ws;
    float* SM = ws;                                        // 4096 f32
    unsigned short* xb  = (unsigned short*)(ws + 4096);    // 3072*512 bf16
    unsigned short* WTb = xb + (size_t)NN * IND;           // 1536*512 bf16
    unsigned short* Qb  = WTb + (size_t)1536 * IND;        // 3 MB each
    unsigned short* KTb = Qb + (size_t)NN * HDTOT;
    unsigned short* VTb = KTb + (size_t)NN * HDTOT;
    float* Opart = (float*)(VTb + (size_t)NN * HDTOT);     // 4*8*3072*64 f32
    float* Dpart = Opart + (size_t)4 * NH * NN * DH;       // 4*8*3072 f32
    const size_t need4 = (size_t)((char*)(Dpart + (size_t)4 * NH * NN) - (char*)d_ws);

    k_prep<<<1537, 256, 0, stream>>>(S, x, Wq, Wk, Wv, SM, xb, WTb);
    k_qkv_mfma<<<dim3(24, 24), 256, 0, stream>>>(xb, WTb, bq, bk, bv,
                                                 angles, SM, Qb, KTb, VTb);
    if (ws_size >= need4) {
        k_attn<12, true><<<dim3(24, 8, 4), 256, 0, stream>>>(Qb, KTb, VTb, Opart, Dpart);
        k_reduce<<<1536, 256, 0, stream>>>(Opart, Dpart, out, 4);
    } else {
        k_attn<48, false><<<dim3(24, 8, 1), 256, 0, stream>>>(Qb, KTb, VTb, out, nullptr);
    }
}